// Round 5
// baseline (677.337 us; speedup 1.0000x reference)
//
#include <hip/hip_runtime.h>

typedef unsigned short u16;
typedef unsigned int u32;
typedef unsigned long long u64;
typedef __attribute__((ext_vector_type(8))) short bf16x8;
typedef __attribute__((ext_vector_type(4))) float f32x4;

__device__ __forceinline__ float b2f(u16 v) {
  union { u32 u; float f; } c; c.u = ((u32)v) << 16; return c.f;
}
__device__ __forceinline__ u16 f2b(float f) {
  union { float f; u32 u; } c; c.f = f;
  return (u16)((c.u + 0x7fffu + ((c.u >> 16) & 1u)) >> 16);
}

// async global->LDS, 16B per lane (global_load_lds_dwordx4).
__device__ __forceinline__ void g2l16(const u16* g, u16* l) {
  __builtin_amdgcn_global_load_lds(
      (const __attribute__((address_space(1))) u32*)g,
      (__attribute__((address_space(3))) u32*)l,
      16, 0, 0);
}

// ---------------- LDS-tiled weight repacks (fp32 in -> bf16 out) -------------
__global__ __launch_bounds__(256)
void repack_qkv_tiled(const float* __restrict__ Wq, const float* __restrict__ Wk,
                      const float* __restrict__ Wv, u16* __restrict__ WT) {
  __shared__ u16 tile[64][65];
  const int sh = blockIdx.y, sel = sh >> 4, h = sh & 15;
  const float* W = (sel == 0) ? Wq : ((sel == 1) ? Wk : Wv);
  const int k0 = blockIdx.x * 64;
  {
    const int d = threadIdx.x & 63, r = threadIdx.x >> 6;
    #pragma unroll
    for (int i = 0; i < 16; ++i) {
      int k = r * 16 + i;
      tile[k][d] = f2b(W[(size_t)h * 65536 + (size_t)(k0 + k) * 64 + d]);
    }
  }
  __syncthreads();
  {
    const int k = threadIdx.x & 63, dd = threadIdx.x >> 6;
    #pragma unroll
    for (int i = 0; i < 16; ++i) {
      int d2 = dd * 16 + i;
      WT[((size_t)sel * 1024 + h * 64 + d2) * 1024 + k0 + k] = tile[k][d2];
    }
  }
}

__global__ __launch_bounds__(256)
void transpose_tiled(const float* __restrict__ W, u16* __restrict__ WT,
                     int N, int K) {
  __shared__ u16 tile[32][33];
  const int bx = blockIdx.x * 32;   // n
  const int by = blockIdx.y * 32;   // k
  const int tx = threadIdx.x & 31, ty = threadIdx.x >> 5;
  #pragma unroll
  for (int i = 0; i < 4; ++i) {
    int k = ty + i * 8;
    tile[k][tx] = f2b(W[(size_t)(by + k) * N + bx + tx]);
  }
  __syncthreads();
  #pragma unroll
  for (int i = 0; i < 4; ++i) {
    int n = ty + i * 8;
    WT[(size_t)(bx + n) * K + by + tx] = tile[tx][n];
  }
}

// ---------------- LayerNorm (C=1024, EPS=1e-3), bf16 out ----------------
__global__ __launch_bounds__(256)
void ln_f32_kernel(const float* __restrict__ X, const float* __restrict__ G,
                   const float* __restrict__ Bt, u16* __restrict__ O) {
  const int row = blockIdx.x;
  const int tid = threadIdx.x;
  const float* xr = X + (size_t)row * 1024;
  float4 xv = *(const float4*)(xr + tid * 4);
  float v0 = xv.x, v1 = xv.y, v2 = xv.z, v3 = xv.w;
  float s = v0 + v1 + v2 + v3;
  float q = v0 * v0 + v1 * v1 + v2 * v2 + v3 * v3;
  #pragma unroll
  for (int off = 32; off > 0; off >>= 1) {
    s += __shfl_down(s, off);
    q += __shfl_down(q, off);
  }
  __shared__ float red[8];
  int wave = tid >> 6, lane = tid & 63;
  if (lane == 0) { red[wave] = s; red[4 + wave] = q; }
  __syncthreads();
  s = red[0] + red[1] + red[2] + red[3];
  q = red[4] + red[5] + red[6] + red[7];
  float mean = s * (1.f / 1024.f);
  float var = q * (1.f / 1024.f) - mean * mean;
  float rstd = rsqrtf(var + 1e-3f);
  float4 gv = *(const float4*)(G + tid * 4);
  float4 bv = *(const float4*)(Bt + tid * 4);
  ushort4 ov;
  ov.x = f2b((v0 - mean) * rstd * gv.x + bv.x);
  ov.y = f2b((v1 - mean) * rstd * gv.y + bv.y);
  ov.z = f2b((v2 - mean) * rstd * gv.z + bv.z);
  ov.w = f2b((v3 - mean) * rstd * gv.w + bv.w);
  *(ushort4*)(O + (size_t)row * 1024 + tid * 4) = ov;
}

__global__ __launch_bounds__(256)
void ln_bf16_kernel(const u16* __restrict__ X, const float* __restrict__ G,
                    const float* __restrict__ Bt, u16* __restrict__ O) {
  const int row = blockIdx.x;
  const int tid = threadIdx.x;
  const u16* xr = X + (size_t)row * 1024;
  ushort4 xv = *(const ushort4*)(xr + tid * 4);
  float v0 = b2f(xv.x), v1 = b2f(xv.y), v2 = b2f(xv.z), v3 = b2f(xv.w);
  float s = v0 + v1 + v2 + v3;
  float q = v0 * v0 + v1 * v1 + v2 * v2 + v3 * v3;
  #pragma unroll
  for (int off = 32; off > 0; off >>= 1) {
    s += __shfl_down(s, off);
    q += __shfl_down(q, off);
  }
  __shared__ float red[8];
  int wave = tid >> 6, lane = tid & 63;
  if (lane == 0) { red[wave] = s; red[4 + wave] = q; }
  __syncthreads();
  s = red[0] + red[1] + red[2] + red[3];
  q = red[4] + red[5] + red[6] + red[7];
  float mean = s * (1.f / 1024.f);
  float var = q * (1.f / 1024.f) - mean * mean;
  float rstd = rsqrtf(var + 1e-3f);
  float4 gv = *(const float4*)(G + tid * 4);
  float4 bv = *(const float4*)(Bt + tid * 4);
  ushort4 ov;
  ov.x = f2b((v0 - mean) * rstd * gv.x + bv.x);
  ov.y = f2b((v1 - mean) * rstd * gv.y + bv.y);
  ov.z = f2b((v2 - mean) * rstd * gv.z + bv.z);
  ov.w = f2b((v3 - mean) * rstd * gv.w + bv.w);
  *(ushort4*)(O + (size_t)row * 1024 + tid * 4) = ov;
}

// ---------------- NT GEMM: A[M,K] * BT[N,K]^T, bf16 in, fp32 acc -------------
// K-loop: width-16 global_load_lds staging with k-chunk XOR swizzle (kills
// 8-way ds_read_b128 bank conflicts). Epilogue: swizzled LDS transpose ->
// coalesced 16B stores (kills RMW write amplification).
// EPI 0: qkv 3-part bias (bf16 out); 1: bias + bf16 residual (bf16 out);
// 2: bias + exact GELU (bf16 out); 3: bias + bf16 residual (fp32 out).
template <int EPI>
__global__ __launch_bounds__(256)
void gemm_nt(const u16* __restrict__ A, const u16* __restrict__ BT,
             void* __restrict__ Cout,
             const float* __restrict__ bias0, const float* __restrict__ bias1,
             const float* __restrict__ bias2, const u16* __restrict__ resid,
             int M, int N, int K) {
  __shared__ __align__(16) u16 smem[8192];      // As=smem[0:4096), Bs=[4096:8192)
  u16* As = smem;
  u16* Bs = smem + 4096;
  const int tid = threadIdx.x;
  const int m0 = blockIdx.y * 128;
  const int n0 = blockIdx.x * 128;
  const int wave = tid >> 6, lane = tid & 63;
  const int wm = wave & 1, wn = wave >> 1;
  const int quad = lane >> 4, l16 = lane & 15;

  f32x4 acc[4][4];
  #pragma unroll
  for (int i = 0; i < 4; ++i)
    #pragma unroll
    for (int j = 0; j < 4; ++j) acc[i][j] = (f32x4){0.f, 0.f, 0.f, 0.f};

  // staging: thread tid covers row=tid>>2 (and +64), k-chunk kc=tid&3.
  // LDS slot kc of row holds global chunk kc ^ f2(row), f2(row)=(row>>1)&3.
  const int rowS = tid >> 2;
  const int kc = tid & 3;
  const int f2s = (tid >> 3) & 3;               // (rowS>>1)&3
  const int kp = (kc ^ f2s) * 8;                // swizzled source k-offset
  const u16* aB0 = A + (size_t)(m0 + rowS) * K + kp;
  const u16* aB1 = A + (size_t)(m0 + rowS + 64) * K + kp;   // f2 same for +64
  const u16* bB0 = BT + (size_t)(n0 + rowS) * K + kp;
  const u16* bB1 = BT + (size_t)(n0 + rowS + 64) * K + kp;
  u16* aD0 = &As[(u32)tid * 8];
  u16* aD1 = &As[(u32)(tid + 256) * 8];
  u16* bD0 = &Bs[(u32)tid * 8];
  u16* bD1 = &Bs[(u32)(tid + 256) * 8];

  // fragment read: row l16-based, want chunk=quad -> slot quad ^ f2(row);
  // f2(row) = (l16>>1)&3 for all i (row = wm*64+i*16+l16, i*16 ≡ 0 mod 8).
  const int kswz = (quad ^ ((l16 >> 1) & 3)) * 8;

  for (int k0 = 0; k0 < K; k0 += 32) {
    g2l16(aB0 + k0, aD0);
    g2l16(aB1 + k0, aD1);
    g2l16(bB0 + k0, bD0);
    g2l16(bB1 + k0, bD1);
    __syncthreads();
    bf16x8 aF[4], bF[4];
    #pragma unroll
    for (int i = 0; i < 4; ++i)
      aF[i] = *(const bf16x8*)&As[(wm * 64 + i * 16 + l16) * 32 + kswz];
    #pragma unroll
    for (int j = 0; j < 4; ++j)
      bF[j] = *(const bf16x8*)&Bs[(wn * 64 + j * 16 + l16) * 32 + kswz];
    #pragma unroll
    for (int i = 0; i < 4; ++i)
      #pragma unroll
      for (int j = 0; j < 4; ++j)
        acc[i][j] = __builtin_amdgcn_mfma_f32_16x16x32_bf16(aF[i], bF[j], acc[i][j], 0, 0, 0);
    __syncthreads();
  }

  // ---- epilogue: stage 64x128 halves through LDS (16B-chunk XOR swizzle),
  // then coalesced stores. C/D layout: col=lane&15, row=quad*4+reg (m89).
  #pragma unroll
  for (int half = 0; half < 2; ++half) {
    if (wm == half) {
      #pragma unroll
      for (int i = 0; i < 4; ++i) {
        const int fsw = (i * 4 + quad) & 7;     // (lrow>>2)&7
        #pragma unroll
        for (int j = 0; j < 4; ++j) {
          const int chunk = (wn * 8 + j * 2 + (l16 >> 3)) ^ fsw;
          const int base = chunk * 8 + (l16 & 7);
          #pragma unroll
          for (int rr = 0; rr < 4; ++rr) {
            const int lrow = i * 16 + quad * 4 + rr;
            smem[lrow * 128 + base] = f2b(acc[i][j][rr]);
          }
        }
      }
    }
    __syncthreads();
    #pragma unroll
    for (int s = 0; s < 4; ++s) {
      const int lrow = s * 16 + (tid >> 4);
      const int chunk = tid & 15;
      const int fsw = (lrow >> 2) & 7;
      bf16x8 cv = *(const bf16x8*)&smem[lrow * 128 + ((chunk ^ fsw) * 8)];
      const int gr = m0 + half * 64 + lrow;
      const int gc = n0 + chunk * 8;
      const float* bp_ = bias0;
      int cb = gc;
      if (EPI == 0) {
        const int selb = gc >> 10;
        bp_ = (selb == 0) ? bias0 : ((selb == 1) ? bias1 : bias2);
        cb = gc & 1023;
      }
      float4 bv0 = *(const float4*)(bp_ + cb);
      float4 bv1 = *(const float4*)(bp_ + cb + 4);
      float vv[8];
      #pragma unroll
      for (int e = 0; e < 8; ++e) {
        float be = (e < 4) ? ((const float*)&bv0)[e] : ((const float*)&bv1)[e - 4];
        vv[e] = b2f(((const u16*)&cv)[e]) + be;
      }
      if (EPI == 2) {
        #pragma unroll
        for (int e = 0; e < 8; ++e)
          vv[e] = 0.5f * vv[e] * (1.0f + erff(vv[e] * 0.70710678118654752f));
      }
      if (EPI == 1 || EPI == 3) {
        bf16x8 rv = *(const bf16x8*)(resid + (size_t)gr * N + gc);
        #pragma unroll
        for (int e = 0; e < 8; ++e) vv[e] += b2f(((const u16*)&rv)[e]);
      }
      if (EPI == 3) {
        float4 o0 = {vv[0], vv[1], vv[2], vv[3]};
        float4 o1 = {vv[4], vv[5], vv[6], vv[7]};
        float* op = (float*)Cout + (size_t)gr * N + gc;
        *(float4*)op = o0;
        *(float4*)(op + 4) = o1;
      } else {
        bf16x8 ov;
        #pragma unroll
        for (int e = 0; e < 8; ++e) ((u16*)&ov)[e] = f2b(vv[e]);
        *(bf16x8*)((u16*)Cout + (size_t)gr * N + gc) = ov;
      }
    }
    __syncthreads();   // half-0 reads done before half-1 overwrites
  }
}

// ---------------- attention (no softmax!): M = scale * K^T V per (b,h) -------
__global__ __launch_bounds__(256)
void attn_m_kernel(const u16* __restrict__ qkv, float* __restrict__ Mbuf) {
  const int bh = blockIdx.x;
  const int b = bh >> 4, h = bh & 15;
  const u16* Kp = qkv + (size_t)b * 1024 * 3072 + 1024 + h * 64;
  const u16* Vp = Kp + 1024;
  __shared__ __align__(16) float Ks[64 * 64];
  __shared__ __align__(16) float Vs[64 * 64];
  const int tid = threadIdx.x;
  const int d1 = tid & 63, d2b = (tid >> 6) * 16;
  const int lr = tid >> 3, lc = (tid & 7) * 8;
  float acc[16];
  #pragma unroll
  for (int j = 0; j < 16; ++j) acc[j] = 0.f;
  for (int t0 = 0; t0 < 1024; t0 += 64) {
    __syncthreads();
    #pragma unroll
    for (int it = 0; it < 2; ++it) {
      int r = it * 32 + lr;
      const u16* ks = Kp + (size_t)(t0 + r) * 3072 + lc;
      const u16* vs = Vp + (size_t)(t0 + r) * 3072 + lc;
      ushort4 a0 = *(const ushort4*)ks;
      ushort4 a1 = *(const ushort4*)(ks + 4);
      ushort4 c0 = *(const ushort4*)vs;
      ushort4 c1 = *(const ushort4*)(vs + 4);
      float* kd = &Ks[r * 64 + lc];
      kd[0] = b2f(a0.x); kd[1] = b2f(a0.y); kd[2] = b2f(a0.z); kd[3] = b2f(a0.w);
      kd[4] = b2f(a1.x); kd[5] = b2f(a1.y); kd[6] = b2f(a1.z); kd[7] = b2f(a1.w);
      float* vd = &Vs[r * 64 + lc];
      vd[0] = b2f(c0.x); vd[1] = b2f(c0.y); vd[2] = b2f(c0.z); vd[3] = b2f(c0.w);
      vd[4] = b2f(c1.x); vd[5] = b2f(c1.y); vd[6] = b2f(c1.z); vd[7] = b2f(c1.w);
    }
    __syncthreads();
    #pragma unroll 8
    for (int tt = 0; tt < 64; ++tt) {
      float kv = Ks[tt * 64 + d1];
      #pragma unroll
      for (int j = 0; j < 16; ++j) acc[j] += kv * Vs[tt * 64 + d2b + j];
    }
  }
  float* Mo = Mbuf + (size_t)bh * 4096 + d1 * 64 + d2b;
  #pragma unroll
  for (int j = 0; j < 16; ++j) Mo[j] = acc[j] * 0.03125f;   // C^-0.5 = 1/32
}

// heads = Q @ M, written directly in concat layout cat[b,t, h*64+d]
__global__ __launch_bounds__(256)
void attn_h_kernel(const u16* __restrict__ qkv, const float* __restrict__ Mbuf,
                   u16* __restrict__ cat) {
  const int bh = blockIdx.x;
  const int tch = blockIdx.y;
  const int b = bh >> 4, h = bh & 15;
  __shared__ __align__(16) float Ms[64 * 64];
  __shared__ __align__(16) float Qs[64 * 65];
  const int tid = threadIdx.x;
  const float* Msrc = Mbuf + (size_t)bh * 4096;
  #pragma unroll
  for (int i = 0; i < 16; ++i) Ms[i * 256 + tid] = Msrc[i * 256 + tid];
  const u16* Qp = qkv + (size_t)(b * 1024 + tch * 64) * 3072 + h * 64;
  {
    const int lr = tid >> 3, lc = (tid & 7) * 8;
    #pragma unroll
    for (int it = 0; it < 2; ++it) {
      int r = it * 32 + lr;
      const u16* qs = Qp + (size_t)r * 3072 + lc;
      ushort4 a0 = *(const ushort4*)qs;
      ushort4 a1 = *(const ushort4*)(qs + 4);
      float* qd = &Qs[r * 65 + lc];
      qd[0] = b2f(a0.x); qd[1] = b2f(a0.y); qd[2] = b2f(a0.z); qd[3] = b2f(a0.w);
      qd[4] = b2f(a1.x); qd[5] = b2f(a1.y); qd[6] = b2f(a1.z); qd[7] = b2f(a1.w);
    }
  }
  __syncthreads();
  const int tl = tid >> 2, db = (tid & 3) * 16;
  float acc[16];
  #pragma unroll
  for (int j = 0; j < 16; ++j) acc[j] = 0.f;
  #pragma unroll 4
  for (int k = 0; k < 64; ++k) {
    float qv = Qs[tl * 65 + k];
    #pragma unroll
    for (int j = 0; j < 16; ++j) acc[j] += qv * Ms[k * 64 + db + j];
  }
  u16* Cp = cat + (size_t)(b * 1024 + tch * 64 + tl) * 1024 + h * 64 + db;
  ushort4 o0 = {f2b(acc[0]), f2b(acc[1]), f2b(acc[2]), f2b(acc[3])};
  ushort4 o1 = {f2b(acc[4]), f2b(acc[5]), f2b(acc[6]), f2b(acc[7])};
  ushort4 o2 = {f2b(acc[8]), f2b(acc[9]), f2b(acc[10]), f2b(acc[11])};
  ushort4 o3 = {f2b(acc[12]), f2b(acc[13]), f2b(acc[14]), f2b(acc[15])};
  *(ushort4*)(Cp + 0) = o0;
  *(ushort4*)(Cp + 4) = o1;
  *(ushort4*)(Cp + 8) = o2;
  *(ushort4*)(Cp + 12) = o3;
}

extern "C" void kernel_launch(void* const* d_in, const int* in_sizes, int n_in,
                              void* d_out, int out_size, void* d_ws, size_t ws_size,
                              hipStream_t stream) {
  (void)in_sizes; (void)n_in; (void)out_size; (void)ws_size;
  const float* x     = (const float*)d_in[0];
  const float* Wq    = (const float*)d_in[1];
  const float* bq    = (const float*)d_in[2];
  const float* Wk    = (const float*)d_in[3];
  const float* bk    = (const float*)d_in[4];
  const float* Wv    = (const float*)d_in[5];
  const float* bv    = (const float*)d_in[6];
  const float* Wp    = (const float*)d_in[7];
  const float* bp    = (const float*)d_in[8];
  const float* W1    = (const float*)d_in[9];
  const float* b1    = (const float*)d_in[10];
  const float* W2    = (const float*)d_in[11];
  const float* b2    = (const float*)d_in[12];
  const float* ln1w  = (const float*)d_in[13];
  const float* ln1b  = (const float*)d_in[14];
  const float* ln2w  = (const float*)d_in[15];
  const float* ln2b  = (const float*)d_in[16];

  char* ws = (char*)d_ws;
  u16* x1    = (u16*)(ws);                        // 16 MiB  [8192,1024] bf16
  u16* qkv   = (u16*)(ws + 16777216);             // 48 MiB  [8192,3072] bf16
  u16* cat   = (u16*)(ws + 67108864);             // 16 MiB  [8192,1024] bf16
  u16* yb    = (u16*)(ws + 83886080);             // 16 MiB  [8192,1024] bf16
  u16* x2    = (u16*)(ws + 100663296);            // 16 MiB  [8192,1024] bf16
  u16* WqkvT = (u16*)(ws + 117440512);            // 6 MiB   [3072,1024] bf16
  u16* WpT   = (u16*)(ws + 123731968);            // 2 MiB   [1024,1024] bf16
  u16* W1T   = (u16*)(ws + 125829120);            // 8 MiB   [4096,1024] bf16
  u16* W2T   = (u16*)(ws + 134217728);            // 8 MiB   [1024,4096] bf16
  float* Mb  = (float*)(ws + 142606336);          // 2 MiB   [128,64,64] fp32
  u16* hb    = (u16*)(ws + 16777216);             // 64 MiB, reuses dead qkv+cat

  repack_qkv_tiled<<<dim3(16, 48), 256, 0, stream>>>(Wq, Wk, Wv, WqkvT);
  transpose_tiled<<<dim3(32, 32), 256, 0, stream>>>(Wp, WpT, 1024, 1024);
  transpose_tiled<<<dim3(128, 32), 256, 0, stream>>>(W1, W1T, 4096, 1024);
  transpose_tiled<<<dim3(32, 128), 256, 0, stream>>>(W2, W2T, 1024, 4096);

  ln_f32_kernel<<<8192, 256, 0, stream>>>(x, ln1w, ln1b, x1);

  gemm_nt<0><<<dim3(24, 64), 256, 0, stream>>>(x1, WqkvT, qkv, bq, bk, bv, nullptr,
                                               8192, 3072, 1024);
  attn_m_kernel<<<128, 256, 0, stream>>>(qkv, Mb);
  attn_h_kernel<<<dim3(128, 16), 256, 0, stream>>>(qkv, Mb, cat);

  gemm_nt<1><<<dim3(8, 64), 256, 0, stream>>>(cat, WpT, yb, bp, nullptr, nullptr, x1,
                                              8192, 1024, 1024);
  ln_bf16_kernel<<<8192, 256, 0, stream>>>(yb, ln2w, ln2b, x2);

  gemm_nt<2><<<dim3(32, 64), 256, 0, stream>>>(x2, W1T, hb, b1, nullptr, nullptr, nullptr,
                                               8192, 4096, 1024);
  gemm_nt<3><<<dim3(8, 64), 256, 0, stream>>>(hb, W2T, d_out, b2, nullptr, nullptr, x2,
                                              8192, 1024, 4096);
}

// Round 7
// 641.959 us; speedup vs baseline: 1.0551x; 1.0551x over previous
//
#include <hip/hip_runtime.h>

typedef unsigned short u16;
typedef unsigned int u32;
typedef unsigned long long u64;
typedef __attribute__((ext_vector_type(8))) short bf16x8;
typedef __attribute__((ext_vector_type(4))) float f32x4;

__device__ __forceinline__ float b2f(u16 v) {
  union { u32 u; float f; } c; c.u = ((u32)v) << 16; return c.f;
}
__device__ __forceinline__ u16 f2b(float f) {
  union { float f; u32 u; } c; c.f = f;
  return (u16)((c.u + 0x7fffu + ((c.u >> 16) & 1u)) >> 16);
}

// async global->LDS, 16B per lane (global_load_lds_dwordx4).
__device__ __forceinline__ void g2l16(const u16* g, u16* l) {
  __builtin_amdgcn_global_load_lds(
      (const __attribute__((address_space(1))) u32*)g,
      (__attribute__((address_space(3))) u32*)l,
      16, 0, 0);
}

// ---------------- LDS-tiled weight repacks (fp32 in -> bf16 out) -------------
__global__ __launch_bounds__(256)
void repack_qkv_tiled(const float* __restrict__ Wq, const float* __restrict__ Wk,
                      const float* __restrict__ Wv, u16* __restrict__ WT) {
  __shared__ u16 tile[64][65];
  const int sh = blockIdx.y, sel = sh >> 4, h = sh & 15;
  const float* W = (sel == 0) ? Wq : ((sel == 1) ? Wk : Wv);
  const int k0 = blockIdx.x * 64;
  {
    const int d = threadIdx.x & 63, r = threadIdx.x >> 6;
    #pragma unroll
    for (int i = 0; i < 16; ++i) {
      int k = r * 16 + i;
      tile[k][d] = f2b(W[(size_t)h * 65536 + (size_t)(k0 + k) * 64 + d]);
    }
  }
  __syncthreads();
  {
    const int k = threadIdx.x & 63, dd = threadIdx.x >> 6;
    #pragma unroll
    for (int i = 0; i < 16; ++i) {
      int d2 = dd * 16 + i;
      WT[((size_t)sel * 1024 + h * 64 + d2) * 1024 + k0 + k] = tile[k][d2];
    }
  }
}

__global__ __launch_bounds__(256)
void transpose_tiled(const float* __restrict__ W, u16* __restrict__ WT,
                     int N, int K) {
  __shared__ u16 tile[32][33];
  const int bx = blockIdx.x * 32;   // n
  const int by = blockIdx.y * 32;   // k
  const int tx = threadIdx.x & 31, ty = threadIdx.x >> 5;
  #pragma unroll
  for (int i = 0; i < 4; ++i) {
    int k = ty + i * 8;
    tile[k][tx] = f2b(W[(size_t)(by + k) * N + bx + tx]);
  }
  __syncthreads();
  #pragma unroll
  for (int i = 0; i < 4; ++i) {
    int n = ty + i * 8;
    WT[(size_t)(bx + n) * K + by + tx] = tile[tx][n];
  }
}

// ---------------- LayerNorm (C=1024, EPS=1e-3), bf16 out ----------------
__global__ __launch_bounds__(256)
void ln_f32_kernel(const float* __restrict__ X, const float* __restrict__ G,
                   const float* __restrict__ Bt, u16* __restrict__ O) {
  const int row = blockIdx.x;
  const int tid = threadIdx.x;
  const float* xr = X + (size_t)row * 1024;
  float4 xv = *(const float4*)(xr + tid * 4);
  float v0 = xv.x, v1 = xv.y, v2 = xv.z, v3 = xv.w;
  float s = v0 + v1 + v2 + v3;
  float q = v0 * v0 + v1 * v1 + v2 * v2 + v3 * v3;
  #pragma unroll
  for (int off = 32; off > 0; off >>= 1) {
    s += __shfl_down(s, off);
    q += __shfl_down(q, off);
  }
  __shared__ float red[8];
  int wave = tid >> 6, lane = tid & 63;
  if (lane == 0) { red[wave] = s; red[4 + wave] = q; }
  __syncthreads();
  s = red[0] + red[1] + red[2] + red[3];
  q = red[4] + red[5] + red[6] + red[7];
  float mean = s * (1.f / 1024.f);
  float var = q * (1.f / 1024.f) - mean * mean;
  float rstd = rsqrtf(var + 1e-3f);
  float4 gv = *(const float4*)(G + tid * 4);
  float4 bv = *(const float4*)(Bt + tid * 4);
  ushort4 ov;
  ov.x = f2b((v0 - mean) * rstd * gv.x + bv.x);
  ov.y = f2b((v1 - mean) * rstd * gv.y + bv.y);
  ov.z = f2b((v2 - mean) * rstd * gv.z + bv.z);
  ov.w = f2b((v3 - mean) * rstd * gv.w + bv.w);
  *(ushort4*)(O + (size_t)row * 1024 + tid * 4) = ov;
}

__global__ __launch_bounds__(256)
void ln_bf16_kernel(const u16* __restrict__ X, const float* __restrict__ G,
                    const float* __restrict__ Bt, u16* __restrict__ O) {
  const int row = blockIdx.x;
  const int tid = threadIdx.x;
  const u16* xr = X + (size_t)row * 1024;
  ushort4 xv = *(const ushort4*)(xr + tid * 4);
  float v0 = b2f(xv.x), v1 = b2f(xv.y), v2 = b2f(xv.z), v3 = b2f(xv.w);
  float s = v0 + v1 + v2 + v3;
  float q = v0 * v0 + v1 * v1 + v2 * v2 + v3 * v3;
  #pragma unroll
  for (int off = 32; off > 0; off >>= 1) {
    s += __shfl_down(s, off);
    q += __shfl_down(q, off);
  }
  __shared__ float red[8];
  int wave = tid >> 6, lane = tid & 63;
  if (lane == 0) { red[wave] = s; red[4 + wave] = q; }
  __syncthreads();
  s = red[0] + red[1] + red[2] + red[3];
  q = red[4] + red[5] + red[6] + red[7];
  float mean = s * (1.f / 1024.f);
  float var = q * (1.f / 1024.f) - mean * mean;
  float rstd = rsqrtf(var + 1e-3f);
  float4 gv = *(const float4*)(G + tid * 4);
  float4 bv = *(const float4*)(Bt + tid * 4);
  ushort4 ov;
  ov.x = f2b((v0 - mean) * rstd * gv.x + bv.x);
  ov.y = f2b((v1 - mean) * rstd * gv.y + bv.y);
  ov.z = f2b((v2 - mean) * rstd * gv.z + bv.z);
  ov.w = f2b((v3 - mean) * rstd * gv.w + bv.w);
  *(ushort4*)(O + (size_t)row * 1024 + tid * 4) = ov;
}

// ---------------- NT GEMM: A[M,K] * BT[N,K]^T, bf16 in, fp32 acc -------------
// BK=64 K-loop: 8x width-16 global_load_lds per iter, 32 MFMA per barrier pair
// (halves barrier-drain count vs BK=32). Row = 128B in LDS, so k-chunk slot is
// XOR-swizzled with (row&7) to spread fragment ds_read_b128 across all banks.
// Epilogue: swizzled LDS transpose -> coalesced 16B stores.
// EPI 0: qkv 3-part bias; 1: bias+residual (bf16 out); 2: bias+GELU;
// 3: bias+residual (fp32 out).
template <int EPI>
__global__ __launch_bounds__(256)
void gemm_nt(const u16* __restrict__ A, const u16* __restrict__ BT,
             void* __restrict__ Cout,
             const float* __restrict__ bias0, const float* __restrict__ bias1,
             const float* __restrict__ bias2, const u16* __restrict__ resid,
             int M, int N, int K) {
  __shared__ __align__(16) u16 smem[16384];     // As=[0:8192), Bs=[8192:16384)
  u16* As = smem;
  u16* Bs = smem + 8192;
  const int tid = threadIdx.x;
  const int m0 = blockIdx.y * 128;
  const int n0 = blockIdx.x * 128;
  const int wave = tid >> 6, lane = tid & 63;
  const int wm = wave & 1, wn = wave >> 1;
  const int quad = lane >> 4, l16 = lane & 15;

  f32x4 acc[4][4];
  #pragma unroll
  for (int i = 0; i < 4; ++i)
    #pragma unroll
    for (int j = 0; j < 4; ++j) acc[i][j] = (f32x4){0.f, 0.f, 0.f, 0.f};

  // staging: thread tid covers row rowS (+32,+64,+96), stored slot = tid&7.
  // Stored slot s of row r holds logical k-chunk s ^ (r&7).
  const int rowS = tid >> 3;                    // 0..31
  const int swz = ((tid & 7) ^ ((tid >> 3) & 7)) * 8;   // source k-offset
  const u16* aB = A + (size_t)(m0 + rowS) * K + swz;
  const u16* bB = BT + (size_t)(n0 + rowS) * K + swz;
  u16* aD = &As[(u32)tid * 8];
  u16* bD = &Bs[(u32)tid * 8];
  const size_t rstep = (size_t)32 * K;          // 32 rows down

  for (int k0 = 0; k0 < K; k0 += 64) {
    #pragma unroll
    for (int cc = 0; cc < 4; ++cc) {
      g2l16(aB + k0 + cc * rstep, aD + cc * 2048);
      g2l16(bB + k0 + cc * rstep, bD + cc * 2048);
    }
    __syncthreads();   // vmcnt drain -> 128x64 tiles staged
    #pragma unroll
    for (int ks = 0; ks < 2; ++ks) {
      // fragment row = wm*64+i*16+l16 -> row&7 = l16&7; logical chunk ks*4+quad
      const int sOff = (((ks * 4 + quad) ^ (l16 & 7)) * 8);
      bf16x8 aF[4], bF[4];
      #pragma unroll
      for (int i = 0; i < 4; ++i)
        aF[i] = *(const bf16x8*)&As[(wm * 64 + i * 16 + l16) * 64 + sOff];
      #pragma unroll
      for (int j = 0; j < 4; ++j)
        bF[j] = *(const bf16x8*)&Bs[(wn * 64 + j * 16 + l16) * 64 + sOff];
      #pragma unroll
      for (int i = 0; i < 4; ++i)
        #pragma unroll
        for (int j = 0; j < 4; ++j)
          acc[i][j] = __builtin_amdgcn_mfma_f32_16x16x32_bf16(aF[i], bF[j], acc[i][j], 0, 0, 0);
    }
    __syncthreads();   // frag reads done before next iter's staging overwrites
  }

  // ---- epilogue: stage 64x128 halves through LDS (16B-chunk XOR swizzle),
  // then coalesced stores. C/D layout: col=lane&15, row=quad*4+reg (m89).
  #pragma unroll
  for (int half = 0; half < 2; ++half) {
    if (wm == half) {
      #pragma unroll
      for (int i = 0; i < 4; ++i) {
        const int fsw = (i * 4 + quad) & 7;     // (lrow>>2)&7
        #pragma unroll
        for (int j = 0; j < 4; ++j) {
          const int chunk = (wn * 8 + j * 2 + (l16 >> 3)) ^ fsw;
          const int base = chunk * 8 + (l16 & 7);
          #pragma unroll
          for (int rr = 0; rr < 4; ++rr) {
            const int lrow = i * 16 + quad * 4 + rr;
            smem[lrow * 128 + base] = f2b(acc[i][j][rr]);
          }
        }
      }
    }
    __syncthreads();
    #pragma unroll
    for (int s = 0; s < 4; ++s) {
      const int lrow = s * 16 + (tid >> 4);
      const int chunk = tid & 15;
      const int fsw = (lrow >> 2) & 7;
      bf16x8 cv = *(const bf16x8*)&smem[lrow * 128 + ((chunk ^ fsw) * 8)];
      const int gr = m0 + half * 64 + lrow;
      const int gc = n0 + chunk * 8;
      const float* bp_ = bias0;
      int cb = gc;
      if (EPI == 0) {
        const int selb = gc >> 10;
        bp_ = (selb == 0) ? bias0 : ((selb == 1) ? bias1 : bias2);
        cb = gc & 1023;
      }
      float4 bv0 = *(const float4*)(bp_ + cb);
      float4 bv1 = *(const float4*)(bp_ + cb + 4);
      float vv[8];
      #pragma unroll
      for (int e = 0; e < 8; ++e) {
        float be = (e < 4) ? ((const float*)&bv0)[e] : ((const float*)&bv1)[e - 4];
        vv[e] = b2f(((const u16*)&cv)[e]) + be;
      }
      if (EPI == 2) {
        #pragma unroll
        for (int e = 0; e < 8; ++e)
          vv[e] = 0.5f * vv[e] * (1.0f + erff(vv[e] * 0.70710678118654752f));
      }
      if (EPI == 1 || EPI == 3) {
        bf16x8 rv = *(const bf16x8*)(resid + (size_t)gr * N + gc);
        #pragma unroll
        for (int e = 0; e < 8; ++e) vv[e] += b2f(((const u16*)&rv)[e]);
      }
      if (EPI == 3) {
        float4 o0 = {vv[0], vv[1], vv[2], vv[3]};
        float4 o1 = {vv[4], vv[5], vv[6], vv[7]};
        float* op = (float*)Cout + (size_t)gr * N + gc;
        *(float4*)op = o0;
        *(float4*)(op + 4) = o1;
      } else {
        bf16x8 ov;
        #pragma unroll
        for (int e = 0; e < 8; ++e) ((u16*)&ov)[e] = f2b(vv[e]);
        *(bf16x8*)((u16*)Cout + (size_t)gr * N + gc) = ov;
      }
    }
    __syncthreads();   // half-0 reads done before half-1 overwrites
  }
}

// ---------------- attention (no softmax!): M = scale * K^T V per (b,h) -------
__global__ __launch_bounds__(256)
void attn_m_kernel(const u16* __restrict__ qkv, float* __restrict__ Mbuf) {
  const int bh = blockIdx.x;
  const int b = bh >> 4, h = bh & 15;
  const u16* Kp = qkv + (size_t)b * 1024 * 3072 + 1024 + h * 64;
  const u16* Vp = Kp + 1024;
  __shared__ __align__(16) float Ks[64 * 64];
  __shared__ __align__(16) float Vs[64 * 64];
  const int tid = threadIdx.x;
  const int d1 = tid & 63, d2b = (tid >> 6) * 16;
  const int lr = tid >> 3, lc = (tid & 7) * 8;
  float acc[16];
  #pragma unroll
  for (int j = 0; j < 16; ++j) acc[j] = 0.f;
  for (int t0 = 0; t0 < 1024; t0 += 64) {
    __syncthreads();
    #pragma unroll
    for (int it = 0; it < 2; ++it) {
      int r = it * 32 + lr;
      const u16* ks = Kp + (size_t)(t0 + r) * 3072 + lc;
      const u16* vs = Vp + (size_t)(t0 + r) * 3072 + lc;
      ushort4 a0 = *(const ushort4*)ks;
      ushort4 a1 = *(const ushort4*)(ks + 4);
      ushort4 c0 = *(const ushort4*)vs;
      ushort4 c1 = *(const ushort4*)(vs + 4);
      float* kd = &Ks[r * 64 + lc];
      kd[0] = b2f(a0.x); kd[1] = b2f(a0.y); kd[2] = b2f(a0.z); kd[3] = b2f(a0.w);
      kd[4] = b2f(a1.x); kd[5] = b2f(a1.y); kd[6] = b2f(a1.z); kd[7] = b2f(a1.w);
      float* vd = &Vs[r * 64 + lc];
      vd[0] = b2f(c0.x); vd[1] = b2f(c0.y); vd[2] = b2f(c0.z); vd[3] = b2f(c0.w);
      vd[4] = b2f(c1.x); vd[5] = b2f(c1.y); vd[6] = b2f(c1.z); vd[7] = b2f(c1.w);
    }
    __syncthreads();
    #pragma unroll 8
    for (int tt = 0; tt < 64; ++tt) {
      float kv = Ks[tt * 64 + d1];
      #pragma unroll
      for (int j = 0; j < 16; ++j) acc[j] += kv * Vs[tt * 64 + d2b + j];
    }
  }
  float* Mo = Mbuf + (size_t)bh * 4096 + d1 * 64 + d2b;
  #pragma unroll
  for (int j = 0; j < 16; ++j) Mo[j] = acc[j] * 0.03125f;   // C^-0.5 = 1/32
}

// heads = Q @ M, written directly in concat layout cat[b,t, h*64+d]
__global__ __launch_bounds__(256)
void attn_h_kernel(const u16* __restrict__ qkv, const float* __restrict__ Mbuf,
                   u16* __restrict__ cat) {
  const int bh = blockIdx.x;
  const int tch = blockIdx.y;
  const int b = bh >> 4, h = bh & 15;
  __shared__ __align__(16) float Ms[64 * 64];
  __shared__ __align__(16) float Qs[64 * 65];
  const int tid = threadIdx.x;
  const float* Msrc = Mbuf + (size_t)bh * 4096;
  #pragma unroll
  for (int i = 0; i < 16; ++i) Ms[i * 256 + tid] = Msrc[i * 256 + tid];
  const u16* Qp = qkv + (size_t)(b * 1024 + tch * 64) * 3072 + h * 64;
  {
    const int lr = tid >> 3, lc = (tid & 7) * 8;
    #pragma unroll
    for (int it = 0; it < 2; ++it) {
      int r = it * 32 + lr;
      const u16* qs = Qp + (size_t)r * 3072 + lc;
      ushort4 a0 = *(const ushort4*)qs;
      ushort4 a1 = *(const ushort4*)(qs + 4);
      float* qd = &Qs[r * 65 + lc];
      qd[0] = b2f(a0.x); qd[1] = b2f(a0.y); qd[2] = b2f(a0.z); qd[3] = b2f(a0.w);
      qd[4] = b2f(a1.x); qd[5] = b2f(a1.y); qd[6] = b2f(a1.z); qd[7] = b2f(a1.w);
    }
  }
  __syncthreads();
  const int tl = tid >> 2, db = (tid & 3) * 16;
  float acc[16];
  #pragma unroll
  for (int j = 0; j < 16; ++j) acc[j] = 0.f;
  #pragma unroll 4
  for (int k = 0; k < 64; ++k) {
    float qv = Qs[tl * 65 + k];
    #pragma unroll
    for (int j = 0; j < 16; ++j) acc[j] += qv * Ms[k * 64 + db + j];
  }
  u16* Cp = cat + (size_t)(b * 1024 + tch * 64 + tl) * 1024 + h * 64 + db;
  ushort4 o0 = {f2b(acc[0]), f2b(acc[1]), f2b(acc[2]), f2b(acc[3])};
  ushort4 o1 = {f2b(acc[4]), f2b(acc[5]), f2b(acc[6]), f2b(acc[7])};
  ushort4 o2 = {f2b(acc[8]), f2b(acc[9]), f2b(acc[10]), f2b(acc[11])};
  ushort4 o3 = {f2b(acc[12]), f2b(acc[13]), f2b(acc[14]), f2b(acc[15])};
  *(ushort4*)(Cp + 0) = o0;
  *(ushort4*)(Cp + 4) = o1;
  *(ushort4*)(Cp + 8) = o2;
  *(ushort4*)(Cp + 12) = o3;
}

extern "C" void kernel_launch(void* const* d_in, const int* in_sizes, int n_in,
                              void* d_out, int out_size, void* d_ws, size_t ws_size,
                              hipStream_t stream) {
  (void)in_sizes; (void)n_in; (void)out_size; (void)ws_size;
  const float* x     = (const float*)d_in[0];
  const float* Wq    = (const float*)d_in[1];
  const float* bq    = (const float*)d_in[2];
  const float* Wk    = (const float*)d_in[3];
  const float* bk    = (const float*)d_in[4];
  const float* Wv    = (const float*)d_in[5];
  const float* bv    = (const float*)d_in[6];
  const float* Wp    = (const float*)d_in[7];
  const float* bp    = (const float*)d_in[8];
  const float* W1    = (const float*)d_in[9];
  const float* b1    = (const float*)d_in[10];
  const float* W2    = (const float*)d_in[11];
  const float* b2    = (const float*)d_in[12];
  const float* ln1w  = (const float*)d_in[13];
  const float* ln1b  = (const float*)d_in[14];
  const float* ln2w  = (const float*)d_in[15];
  const float* ln2b  = (const float*)d_in[16];

  char* ws = (char*)d_ws;
  u16* x1    = (u16*)(ws);                        // 16 MiB  [8192,1024] bf16
  u16* qkv   = (u16*)(ws + 16777216);             // 48 MiB  [8192,3072] bf16
  u16* cat   = (u16*)(ws + 67108864);             // 16 MiB  [8192,1024] bf16
  u16* yb    = (u16*)(ws + 83886080);             // 16 MiB  [8192,1024] bf16
  u16* x2    = (u16*)(ws + 100663296);            // 16 MiB  [8192,1024] bf16
  u16* WqkvT = (u16*)(ws + 117440512);            // 6 MiB   [3072,1024] bf16
  u16* WpT   = (u16*)(ws + 123731968);            // 2 MiB   [1024,1024] bf16
  u16* W1T   = (u16*)(ws + 125829120);            // 8 MiB   [4096,1024] bf16
  u16* W2T   = (u16*)(ws + 134217728);            // 8 MiB   [1024,4096] bf16
  float* Mb  = (float*)(ws + 142606336);          // 2 MiB   [128,64,64] fp32
  u16* hb    = (u16*)(ws + 16777216);             // 64 MiB, reuses dead qkv+cat

  repack_qkv_tiled<<<dim3(16, 48), 256, 0, stream>>>(Wq, Wk, Wv, WqkvT);
  transpose_tiled<<<dim3(32, 32), 256, 0, stream>>>(Wp, WpT, 1024, 1024);
  transpose_tiled<<<dim3(128, 32), 256, 0, stream>>>(W1, W1T, 4096, 1024);
  transpose_tiled<<<dim3(32, 128), 256, 0, stream>>>(W2, W2T, 1024, 4096);

  ln_f32_kernel<<<8192, 256, 0, stream>>>(x, ln1w, ln1b, x1);

  gemm_nt<0><<<dim3(24, 64), 256, 0, stream>>>(x1, WqkvT, qkv, bq, bk, bv, nullptr,
                                               8192, 3072, 1024);
  attn_m_kernel<<<128, 256, 0, stream>>>(qkv, Mb);
  attn_h_kernel<<<dim3(128, 16), 256, 0, stream>>>(qkv, Mb, cat);

  gemm_nt<1><<<dim3(8, 64), 256, 0, stream>>>(cat, WpT, yb, bp, nullptr, nullptr, x1,
                                              8192, 1024, 1024);
  ln_bf16_kernel<<<8192, 256, 0, stream>>>(yb, ln2w, ln2b, x2);

  gemm_nt<2><<<dim3(32, 64), 256, 0, stream>>>(x2, W1T, hb, b1, nullptr, nullptr, nullptr,
                                               8192, 4096, 1024);
  gemm_nt<3><<<dim3(8, 64), 256, 0, stream>>>(hb, W2T, d_out, b2, nullptr, nullptr, x2,
                                              8192, 1024, 4096);
}